// Round 7
// baseline (716.596 us; speedup 1.0000x reference)
//
#include <hip/hip_runtime.h>
#include <math.h>

#define HD   64
#define EIN  8
#define SAS  168          // sA/sW1 row stride in u16 (336 B): bank step 20 -> 2-way max (free)
#define W2S  72           // sW2 row stride in u16 (144 B): bank step 4 -> 2-way (free)
#define NORM_INV 0.01f
#define NTH  512          // 8 waves/block, one shared weight copy
#define NBLK 512          // 2 blocks/CU x 256 CUs
#define NWAVES (NBLK * (NTH / 64))

typedef short bf16x8 __attribute__((ext_vector_type(8)));
typedef float f32x4  __attribute__((ext_vector_type(4)));
typedef float f4v    __attribute__((ext_vector_type(4)));

__device__ __forceinline__ unsigned short f2bf(float f) {
    union { float f; unsigned u; } v; v.f = f;
    unsigned r = v.u + 0x7FFFu + ((v.u >> 16) & 1u);
    return (unsigned short)(r >> 16);
}
__device__ __forceinline__ unsigned pk2(float a, float b) {
    return (unsigned)f2bf(a) | ((unsigned)f2bf(b) << 16);
}
__device__ __forceinline__ float silu_f(float x) {
    return x * __builtin_amdgcn_rcpf(1.0f + __expf(-x));
}

__global__ void prep_out_kernel(const float* __restrict__ coord,
                                float* __restrict__ out, int n3) {
    int i = blockIdx.x * blockDim.x + threadIdx.x;
    if (i < n3) out[i] = coord[i];
}

// Wave-owned barrier-free pipeline (r5 structure) + register prefetch that fits:
// __launch_bounds__(512,4) caps VGPRs at 128; biases NOT reg-cached so the
// hN[8] prefetch stays in registers instead of being sunk/spilled (r6 failure).
// Strided group sweep, plain (cached) loads, 8 waves sharing one weight copy.
__global__ __launch_bounds__(NTH, 4) void egnn_mfma_kernel(
    const float* __restrict__ h,
    const float* __restrict__ coord,
    const int*   __restrict__ eidx,
    const float* __restrict__ eattr,
    const float* __restrict__ W1f,    // [136][64] fp32
    const float* __restrict__ W2f,    // [64][64] fp32
    const float* __restrict__ b1,
    const float* __restrict__ b2,
    const float* __restrict__ W3,
    float* __restrict__ out,
    int E_)
{
    __shared__ unsigned short sW1[64 * SAS];      // 21504 B
    __shared__ unsigned short sW2[64 * W2S];      //  9216 B
    __shared__ float sB1[64], sB2[64], sW3[64];   //   768 B
    __shared__ unsigned short sA[128 * SAS];      // 43008 B (8 waves x 16 rows)

    const int t = threadIdx.x;

    // ---- weights -> LDS (once per block) ----
    for (int i = t; i < 136 * 64; i += NTH) {
        int k = i >> 6, n = i & 63;
        sW1[n * SAS + k] = f2bf(W1f[i]);
    }
    for (int i = t; i < 24 * 64; i += NTH) {      // zero-pad W1 k=136..159
        int n = i / 24, k = 136 + (i - n * 24);
        sW1[n * SAS + k] = 0;
    }
    for (int i = t; i < 64 * 64; i += NTH) {
        int k = i >> 6, n = i & 63;
        sW2[n * W2S + k] = f2bf(W2f[i]);
    }
    if (t < 64) sB1[t] = b1[t];
    else if (t < 128) sB2[t - 64] = b2[t - 64];
    else if (t < 192) sW3[t - 128] = W3[t - 128];
    __syncthreads();                               // the ONLY barrier

    const int w = t >> 6, lane = t & 63;
    const int m = lane & 15, q = lane >> 4;
    const int sm = lane >> 2, sp = lane & 3;       // staging: 4 lanes per edge

    unsigned short* stageRow = sA + (16 * w + sm) * SAS;
    unsigned short* fragRow  = sA + (16 * w + m) * SAS;

    // persistent zero-pad k=136..159 of this wave's rows (X1 aliases only k=0..63)
    if (sp < 3) {
        uint4 z; z.x = 0; z.y = 0; z.z = 0; z.w = 0;
        *((uint4*)(stageRow + 136 + sp * 8)) = z;
    }

    const int ngroups = (E_ + 15) >> 4;
    int g = blockIdx.x * (NTH / 64) + w;           // strided sweep (r5 pattern)
    if (g >= ngroups) return;

    // prefetch state
    f4v  hN[8];            // this lane's 128 B half-row of h (fp32)
    f4v  epN;              // sp odd: one float4 of edge_attr
    int  nodeN;
    uint4 pk[4];           // packed bf16
    unsigned pkE0, pkE1;
    int  node;

    auto load_group = [&](int gg) {
        int e = gg * 16 + sm;
        int ec = (e < E_) ? e : (E_ - 1);
        nodeN = (sp < 2) ? eidx[ec] : eidx[(size_t)E_ + ec];
        const f4v* src = (const f4v*)(h + (size_t)nodeN * HD) + (sp & 1) * 8;
#pragma unroll
        for (int i = 0; i < 8; ++i) hN[i] = src[i];
        if (sp & 1) epN = ((const f4v*)(eattr + (size_t)ec * EIN))[sp >> 1];
    };
    auto pack_group = [&]() {
#pragma unroll
        for (int i = 0; i < 4; ++i) {
            f4v a = hN[2 * i], b = hN[2 * i + 1];
            pk[i].x = pk2(a.x, a.y); pk[i].y = pk2(a.z, a.w);
            pk[i].z = pk2(b.x, b.y); pk[i].w = pk2(b.z, b.w);
        }
        pkE0 = pk2(epN.x, epN.y); pkE1 = pk2(epN.z, epN.w);
        node = nodeN;
    };
    auto stage_write = [&]() {
        uint4* dst = (uint4*)stageRow + sp * 4;    // k in [32*sp, 32*sp+32)
#pragma unroll
        for (int i = 0; i < 4; ++i) dst[i] = pk[i];
        if (sp & 1) {                              // edge_attr k=128..135
            uint2 v; v.x = pkE0; v.y = pkE1;
            *((uint2*)(stageRow + 128 + (sp >> 1) * 4)) = v;
        }
    };

    // prologue: group g fully staged
    load_group(g);
    pack_group();
    stage_write();

    for (;;) {
        // epilogue indices for current group via shfl; issue coord loads early
        int rI = __shfl(node, 4 * m);
        int cI = __shfl(node, 4 * m + 2);
        float cr = 0.f, cc = 0.f;
        if (q < 3) { cr = coord[rI * 3 + q]; cc = coord[cI * 3 + q]; }

        // issue next group's gathers; consumed only after layer 2 (max cover)
        int gn = g + NWAVES;
        bool more = (gn < ngroups);
        if (more) load_group(gn);

        // ---------- layer 1: D1[n2][e] = sum_k W1[n2][k] * inp[e][k] ----------
        f32x4 acc1[4] = {};
#pragma unroll
        for (int s = 0; s < 5; ++s) {
            bf16x8 bfrag = *(const bf16x8*)(fragRow + s * 32 + q * 8);
#pragma unroll
            for (int nt = 0; nt < 4; ++nt) {
                bf16x8 afrag = *(const bf16x8*)(sW1 + (16 * nt + m) * SAS + s * 32 + q * 8);
                acc1[nt] = __builtin_amdgcn_mfma_f32_16x16x32_bf16(afrag, bfrag, acc1[nt], 0, 0, 0);
            }
        }

        // silu(+b1) -> X1 at row offset 0 (k=0..63), packed b64 per lane
#pragma unroll
        for (int nt = 0; nt < 4; ++nt) {
            float4 bb = *(const float4*)(&sB1[16 * nt + 4 * q]);
            ushort4 o;
            o.x = f2bf(silu_f(acc1[nt][0] + bb.x));
            o.y = f2bf(silu_f(acc1[nt][1] + bb.y));
            o.z = f2bf(silu_f(acc1[nt][2] + bb.z));
            o.w = f2bf(silu_f(acc1[nt][3] + bb.w));
            *((ushort4*)(fragRow + 16 * nt + 4 * q)) = o;
        }

        // ---------- layer 2: D2[n2][e] = sum_k W2[n2][k] * X1[e][k] ----------
        f32x4 acc2[4] = {};
#pragma unroll
        for (int s = 0; s < 2; ++s) {
            bf16x8 bfrag = *(const bf16x8*)(fragRow + s * 32 + q * 8);
#pragma unroll
            for (int nt = 0; nt < 4; ++nt) {
                bf16x8 afrag = *(const bf16x8*)(sW2 + (16 * nt + m) * W2S + s * 32 + q * 8);
                acc2[nt] = __builtin_amdgcn_mfma_f32_16x16x32_bf16(afrag, bfrag, acc2[nt], 0, 0, 0);
            }
        }

        // pack + stage next group now (vmcnt wait lands here, after ~1000 cyc
        // of cover; same rows safe: this wave's X1 reads already issued)
        if (more) { pack_group(); stage_write(); }

        // ---------- epilogue: scal = silu(X2) . W3, all in registers ----------
        float p = 0.f;
#pragma unroll
        for (int nt = 0; nt < 4; ++nt) {
            float4 b2v = *(const float4*)(&sB2[16 * nt + 4 * q]);
            float4 w3v = *(const float4*)(&sW3[16 * nt + 4 * q]);
            p = fmaf(silu_f(acc2[nt][0] + b2v.x), w3v.x, p);
            p = fmaf(silu_f(acc2[nt][1] + b2v.y), w3v.y, p);
            p = fmaf(silu_f(acc2[nt][2] + b2v.z), w3v.z, p);
            p = fmaf(silu_f(acc2[nt][3] + b2v.w), w3v.w, p);
        }
        p += __shfl_xor(p, 16);
        p += __shfl_xor(p, 32);

        // distributed coord-diff: lane (q,m) owns component q of edge m
        float cd = cr - cc;                        // q==3 lanes contribute 0
        float r2 = cd * cd;
        r2 += __shfl_xor(r2, 16);
        r2 += __shfl_xor(r2, 32);
        int e2 = g * 16 + m;
        if (e2 < E_ && q < 3) {
            float inv = __builtin_amdgcn_rcpf(sqrtf(r2 + 1e-8f) + 1.0f);
            atomicAdd(&out[rI * 3 + q], cd * (p * NORM_INV * inv));
        }

        if (!more) break;
        g = gn;
    }
}

extern "C" void kernel_launch(void* const* d_in, const int* in_sizes, int n_in,
                              void* d_out, int out_size, void* d_ws, size_t ws_size,
                              hipStream_t stream) {
    const float* h         = (const float*)d_in[0];
    const float* coord     = (const float*)d_in[1];
    const int*   eidx      = (const int*)  d_in[2];
    const float* edge_attr = (const float*)d_in[3];
    const float* W1        = (const float*)d_in[4];
    const float* b1        = (const float*)d_in[5];
    const float* W2        = (const float*)d_in[6];
    const float* b2        = (const float*)d_in[7];
    const float* W3        = (const float*)d_in[8];
    float* out = (float*)d_out;

    int E_ = in_sizes[2] / 2;    // edge_index is [2, E]
    int n3 = out_size;           // N*3

    hipLaunchKernelGGL(prep_out_kernel, dim3((n3 + 255) / 256), dim3(256), 0, stream,
                       coord, out, n3);
    hipLaunchKernelGGL(egnn_mfma_kernel, dim3(NBLK), dim3(NTH), 0, stream,
                       h, coord, eidx, edge_attr, W1, W2, b1, b2, W3, out, E_);
}

// Round 8
// 500.099 us; speedup vs baseline: 1.4329x; 1.4329x over previous
//
#include <hip/hip_runtime.h>
#include <math.h>

#define HD   64
#define EIN  8
#define SAS  168          // sA/sW1 row stride in u16 (336 B): bank step 20 -> conflict-light
#define W2S  72           // sW2 row stride in u16 (144 B)
#define NORM_INV 0.01f
#define NTH  512          // 8 waves/block, one shared weight copy
#define NBLK 512          // 2 blocks/CU x 256 CUs
#define NWAVES (NBLK * (NTH / 64))

typedef short bf16x8 __attribute__((ext_vector_type(8)));
typedef float f32x4  __attribute__((ext_vector_type(4)));
typedef float f4v    __attribute__((ext_vector_type(4)));

__device__ __forceinline__ unsigned short f2bf(float f) {
    union { float f; unsigned u; } v; v.f = f;
    unsigned r = v.u + 0x7FFFu + ((v.u >> 16) & 1u);
    return (unsigned short)(r >> 16);
}
__device__ __forceinline__ unsigned pk2(float a, float b) {
    return (unsigned)f2bf(a) | ((unsigned)f2bf(b) << 16);
}
__device__ __forceinline__ float silu_f(float x) {
    return x * __builtin_amdgcn_rcpf(1.0f + __expf(-x));
}

// prep: coord -> out copy, h -> bf16 table in ws (when ws fits)
__global__ void prep_h_kernel(const float* __restrict__ h, unsigned short* __restrict__ hbf,
                              int npairs, const float* __restrict__ coord,
                              float* __restrict__ out, int n3) {
    int i = blockIdx.x * blockDim.x + threadIdx.x;
    if (i < npairs) {
        float2 v = reinterpret_cast<const float2*>(h)[i];
        ushort2 o; o.x = f2bf(v.x); o.y = f2bf(v.y);
        reinterpret_cast<ushort2*>(hbf)[i] = o;
    }
    if (i < n3) out[i] = coord[i];
}

__global__ void prep_out_kernel(const float* __restrict__ coord,
                                float* __restrict__ out, int n3) {
    int i = blockIdx.x * blockDim.x + threadIdx.x;
    if (i < n3) out[i] = coord[i];
}

// r5's proven barrier-free wave-owned pipeline, NO register prefetch (r6/r7
// both made the compiler spill/sink), 8 waves per block sharing one weight
// copy (16 waves/CU), h gathered as bf16 when HB (half the gather bytes).
template <bool HB>
__global__ __launch_bounds__(NTH, 4) void egnn_mfma_kernel(
    const float* __restrict__ h,             // fp32 h (used when !HB)
    const unsigned short* __restrict__ hbf,  // bf16 h table in ws (when HB)
    const float* __restrict__ coord,
    const int*   __restrict__ eidx,
    const float* __restrict__ eattr,
    const float* __restrict__ W1f,    // [136][64] fp32
    const float* __restrict__ W2f,    // [64][64] fp32
    const float* __restrict__ b1,
    const float* __restrict__ b2,
    const float* __restrict__ W3,
    float* __restrict__ out,
    int E_)
{
    __shared__ unsigned short sW1[64 * SAS];      // 21504 B
    __shared__ unsigned short sW2[64 * W2S];      //  9216 B
    __shared__ float sB1[64], sB2[64], sW3[64];   //   768 B
    __shared__ unsigned short sA[128 * SAS];      // 43008 B (8 waves x 16 rows)

    const int t = threadIdx.x;

    // ---- weights -> LDS (once per block) ----
    for (int i = t; i < 136 * 64; i += NTH) {
        int k = i >> 6, n = i & 63;
        sW1[n * SAS + k] = f2bf(W1f[i]);
    }
    for (int i = t; i < 24 * 64; i += NTH) {      // zero-pad W1 k=136..159
        int n = i / 24, k = 136 + (i - n * 24);
        sW1[n * SAS + k] = 0;
    }
    for (int i = t; i < 64 * 64; i += NTH) {
        int k = i >> 6, n = i & 63;
        sW2[n * W2S + k] = f2bf(W2f[i]);
    }
    if (t < 64) sB1[t] = b1[t];
    else if (t < 128) sB2[t - 64] = b2[t - 64];
    else if (t < 192) sW3[t - 128] = W3[t - 128];
    __syncthreads();                               // the ONLY barrier

    const int w = t >> 6, lane = t & 63;
    const int m = lane & 15, q = lane >> 4;
    const int sm = lane >> 2, sp = lane & 3;       // staging: 4 lanes per edge

    unsigned short* stageRow = sA + (16 * w + sm) * SAS;
    unsigned short* fragRow  = sA + (16 * w + m) * SAS;

    // zero-pad k=136..159 of this wave's rows once (X1 aliases only k=0..63)
    if (sp < 3) {
        uint4 z; z.x = 0; z.y = 0; z.z = 0; z.w = 0;
        *((uint4*)(stageRow + 136 + sp * 8)) = z;
    }

    const int ngroups = (E_ + 15) >> 4;
    for (int g = blockIdx.x * (NTH / 64) + w; g < ngroups; g += NWAVES) {
        // ---------- stage 16 edges (this wave's rows; inline, no prefetch) ----------
        int node;
        {
            int e = g * 16 + sm;
            int ec = (e < E_) ? e : (E_ - 1);
            node = (sp < 2) ? eidx[ec] : eidx[(size_t)E_ + ec];
            uint4* dst = (uint4*)stageRow + sp * 4;    // k in [32*sp, 32*sp+32)
            if (HB) {
                // bf16 table: this lane's 64 B quarter-row, straight copy
                const uint4* src = (const uint4*)(hbf + (size_t)node * HD) + (sp & 1) * 4;
#pragma unroll
                for (int i = 0; i < 4; ++i) dst[i] = src[i];
            } else {
                const f4v* src = (const f4v*)(h + (size_t)node * HD) + (sp & 1) * 8;
#pragma unroll
                for (int i = 0; i < 4; ++i) {
                    f4v a = src[2 * i], b = src[2 * i + 1];
                    uint4 v;
                    v.x = pk2(a.x, a.y); v.y = pk2(a.z, a.w);
                    v.z = pk2(b.x, b.y); v.w = pk2(b.z, b.w);
                    dst[i] = v;
                }
            }
            if (sp & 1) {                              // edge_attr k=128..135
                f4v ep = ((const f4v*)(eattr + (size_t)ec * EIN))[sp >> 1];
                uint2 v; v.x = pk2(ep.x, ep.y); v.y = pk2(ep.z, ep.w);
                *((uint2*)(stageRow + 128 + (sp >> 1) * 4)) = v;
            }
        }

        // epilogue indices via shfl (no eidx re-read); coord loads issued early
        int rI = __shfl(node, 4 * m);
        int cI = __shfl(node, 4 * m + 2);
        float cr = 0.f, cc = 0.f;
        if (q < 3) { cr = coord[rI * 3 + q]; cc = coord[cI * 3 + q]; }

        // ---------- layer 1: D1[n2][e] = sum_k W1[n2][k] * inp[e][k] ----------
        f32x4 acc1[4] = {};
#pragma unroll
        for (int s = 0; s < 5; ++s) {
            bf16x8 bfrag = *(const bf16x8*)(fragRow + s * 32 + q * 8);
#pragma unroll
            for (int nt = 0; nt < 4; ++nt) {
                bf16x8 afrag = *(const bf16x8*)(sW1 + (16 * nt + m) * SAS + s * 32 + q * 8);
                acc1[nt] = __builtin_amdgcn_mfma_f32_16x16x32_bf16(afrag, bfrag, acc1[nt], 0, 0, 0);
            }
        }

        // silu(+b1) -> X1 at row offset 0 (k=0..63), packed b64 per lane
#pragma unroll
        for (int nt = 0; nt < 4; ++nt) {
            float4 bb = *(const float4*)(&sB1[16 * nt + 4 * q]);
            ushort4 o;
            o.x = f2bf(silu_f(acc1[nt][0] + bb.x));
            o.y = f2bf(silu_f(acc1[nt][1] + bb.y));
            o.z = f2bf(silu_f(acc1[nt][2] + bb.z));
            o.w = f2bf(silu_f(acc1[nt][3] + bb.w));
            *((ushort4*)(fragRow + 16 * nt + 4 * q)) = o;
        }

        // ---------- layer 2: D2[n2][e] = sum_k W2[n2][k] * X1[e][k] ----------
        f32x4 acc2[4] = {};
#pragma unroll
        for (int s = 0; s < 2; ++s) {
            bf16x8 bfrag = *(const bf16x8*)(fragRow + s * 32 + q * 8);
#pragma unroll
            for (int nt = 0; nt < 4; ++nt) {
                bf16x8 afrag = *(const bf16x8*)(sW2 + (16 * nt + m) * W2S + s * 32 + q * 8);
                acc2[nt] = __builtin_amdgcn_mfma_f32_16x16x32_bf16(afrag, bfrag, acc2[nt], 0, 0, 0);
            }
        }

        // ---------- epilogue: scal = silu(X2) . W3, all in registers ----------
        float p = 0.f;
#pragma unroll
        for (int nt = 0; nt < 4; ++nt) {
            float4 b2v = *(const float4*)(&sB2[16 * nt + 4 * q]);
            float4 w3v = *(const float4*)(&sW3[16 * nt + 4 * q]);
            p = fmaf(silu_f(acc2[nt][0] + b2v.x), w3v.x, p);
            p = fmaf(silu_f(acc2[nt][1] + b2v.y), w3v.y, p);
            p = fmaf(silu_f(acc2[nt][2] + b2v.z), w3v.z, p);
            p = fmaf(silu_f(acc2[nt][3] + b2v.w), w3v.w, p);
        }
        p += __shfl_xor(p, 16);
        p += __shfl_xor(p, 32);

        // distributed coord-diff: lane (q,m) owns component q of edge m
        float cd = cr - cc;                        // q==3 lanes contribute 0
        float r2 = cd * cd;
        r2 += __shfl_xor(r2, 16);
        r2 += __shfl_xor(r2, 32);
        int e2 = g * 16 + m;
        if (e2 < E_ && q < 3) {
            float inv = __builtin_amdgcn_rcpf(sqrtf(r2 + 1e-8f) + 1.0f);
            atomicAdd(&out[rI * 3 + q], cd * (p * NORM_INV * inv));
        }
    }
}

extern "C" void kernel_launch(void* const* d_in, const int* in_sizes, int n_in,
                              void* d_out, int out_size, void* d_ws, size_t ws_size,
                              hipStream_t stream) {
    const float* h         = (const float*)d_in[0];
    const float* coord     = (const float*)d_in[1];
    const int*   eidx      = (const int*)  d_in[2];
    const float* edge_attr = (const float*)d_in[3];
    const float* W1        = (const float*)d_in[4];
    const float* b1        = (const float*)d_in[5];
    const float* W2        = (const float*)d_in[6];
    const float* b2        = (const float*)d_in[7];
    const float* W3        = (const float*)d_in[8];
    float* out = (float*)d_out;

    int E_ = in_sizes[2] / 2;    // edge_index is [2, E]
    int n3 = out_size;           // N*3
    int nf = in_sizes[0];        // N*HD floats of h

    if (ws_size >= (size_t)nf * 2) {             // bf16 h table fits (6.4 MB)
        unsigned short* hbf = (unsigned short*)d_ws;
        int npairs = nf / 2;
        int pgrid = (npairs > n3 ? npairs : n3);
        hipLaunchKernelGGL(prep_h_kernel, dim3((pgrid + 511) / 512), dim3(512), 0, stream,
                           h, hbf, npairs, coord, out, n3);
        hipLaunchKernelGGL((egnn_mfma_kernel<true>), dim3(NBLK), dim3(NTH), 0, stream,
                           h, hbf, coord, eidx, edge_attr, W1, W2, b1, b2, W3, out, E_);
    } else {
        hipLaunchKernelGGL(prep_out_kernel, dim3((n3 + 511) / 512), dim3(512), 0, stream,
                           coord, out, n3);
        hipLaunchKernelGGL((egnn_mfma_kernel<false>), dim3(NBLK), dim3(NTH), 0, stream,
                           h, (const unsigned short*)nullptr, coord, eidx, edge_attr,
                           W1, W2, b1, b2, W3, out, E_);
    }
}